// Round 1
// baseline (1006.781 us; speedup 1.0000x reference)
//
#include <hip/hip_runtime.h>
#include <hip/hip_bf16.h>

#define GN 100000   // nodes
#define GE 3200000  // edges
#define GH 128      // feature/hidden width
#define GA 1024     // actions
#define GB 256      // graphs

// ---------------- CSR build ----------------

__global__ void k_count(const int* __restrict__ dst, int* __restrict__ deg) {
    int e = blockIdx.x * 256 + threadIdx.x;
    if (e < GE) atomicAdd(&deg[dst[e]], 1);
}

// per-1024-chunk local exclusive scan; chunk totals to bsum
__global__ void k_scan1(const int* __restrict__ deg, int* __restrict__ loc,
                        int* __restrict__ bsum) {
    int t = threadIdx.x;
    int idx = blockIdx.x * 1024 + t * 4;
    int v0 = (idx + 0 < GN) ? deg[idx + 0] : 0;
    int v1 = (idx + 1 < GN) ? deg[idx + 1] : 0;
    int v2 = (idx + 2 < GN) ? deg[idx + 2] : 0;
    int v3 = (idx + 3 < GN) ? deg[idx + 3] : 0;
    int s = v0 + v1 + v2 + v3;
    int lane = t & 63, w = t >> 6;
    int x = s;
#pragma unroll
    for (int off = 1; off < 64; off <<= 1) {
        int y = __shfl_up(x, off);
        if (lane >= off) x += y;
    }
    __shared__ int wsum[4];
    if (lane == 63) wsum[w] = x;
    __syncthreads();
    int wo = 0;
#pragma unroll
    for (int i = 0; i < 4; i++)
        if (i < w) wo += wsum[i];
    int run = wo + x - s;  // exclusive prefix of this thread's 4-sum
    if (idx + 0 < GN) loc[idx + 0] = run;
    run += v0;
    if (idx + 1 < GN) loc[idx + 1] = run;
    run += v1;
    if (idx + 2 < GN) loc[idx + 2] = run;
    run += v2;
    if (idx + 3 < GN) loc[idx + 3] = run;
    if (t == 255) bsum[blockIdx.x] = wo + x;  // chunk total
}

__global__ void k_scan2(int* __restrict__ bsum, int nb) {
    __shared__ int s[128];
    int t = threadIdx.x;
    s[t] = (t < nb) ? bsum[t] : 0;
    __syncthreads();
    if (t == 0) {
        int run = 0;
        for (int i = 0; i < nb; i++) { int v = s[i]; s[i] = run; run += v; }
    }
    __syncthreads();
    if (t < nb) bsum[t] = s[t];
}

__global__ void k_scan3(const int* __restrict__ bsum, const int* __restrict__ deg,
                        int* __restrict__ offsets, int* __restrict__ cursor,
                        float* __restrict__ dinv) {
    int i = blockIdx.x * 256 + threadIdx.x;
    if (i < GN) {
        int off = offsets[i] + bsum[i >> 10];  // offsets currently holds local scan
        offsets[i] = off;
        cursor[i] = off;
        dinv[i] = rsqrtf((float)(deg[i] + 1));  // +1 self-loop
    }
    if (i == 0) offsets[GN] = GE;
}

__global__ void k_scatter(const int* __restrict__ src, const int* __restrict__ dst,
                          int* __restrict__ cursor, int* __restrict__ csr_src) {
    int e = blockIdx.x * 256 + threadIdx.x;
    if (e < GE) {
        int d = dst[e];
        int pos = atomicAdd(&cursor[d], 1);
        csr_src[pos] = src[e];
    }
}

// ---------------- GEMM: C[row] = dinv[row] * (A[row] @ W), A:[GN,128] W:[128,128]
__global__ __launch_bounds__(256) void k_gemm(const float* __restrict__ A,
                                              const float* __restrict__ W,
                                              const float* __restrict__ dinv,
                                              float* __restrict__ C) {
    __shared__ float Ws[64][128];
    __shared__ float As[32][68];
    int t = threadIdx.x;
    int ty = t >> 4, tx = t & 15;
    int row0 = blockIdx.x * 32;

    float4 accA[2] = {{0, 0, 0, 0}, {0, 0, 0, 0}};  // cols tx*4..+3
    float4 accB[2] = {{0, 0, 0, 0}, {0, 0, 0, 0}};  // cols 64+tx*4..+3

    for (int kb = 0; kb < 128; kb += 64) {
        // stage W k-slab: 64x128 floats, 8 float4 per thread
#pragma unroll
        for (int i = 0; i < 8; i++) {
            int q = t + 256 * i;
            int kr = q >> 5;
            int c4 = (q & 31) << 2;
            *(float4*)&Ws[kr][c4] = *(const float4*)&W[(kb + kr) * 128 + c4];
        }
        // stage A tile: 32x64 floats, 2 float4 per thread
#pragma unroll
        for (int i = 0; i < 2; i++) {
            int q = t + 256 * i;
            int ar = q >> 4;
            int c4 = (q & 15) << 2;
            *(float4*)&As[ar][c4] = *(const float4*)&A[(size_t)(row0 + ar) * 128 + kb + c4];
        }
        __syncthreads();
#pragma unroll 8
        for (int k = 0; k < 64; k++) {
            float a0 = As[ty * 2 + 0][k];
            float a1 = As[ty * 2 + 1][k];
            float4 b0 = *(float4*)&Ws[k][tx * 4];
            float4 b1 = *(float4*)&Ws[k][64 + tx * 4];
            accA[0].x = fmaf(a0, b0.x, accA[0].x); accA[0].y = fmaf(a0, b0.y, accA[0].y);
            accA[0].z = fmaf(a0, b0.z, accA[0].z); accA[0].w = fmaf(a0, b0.w, accA[0].w);
            accB[0].x = fmaf(a0, b1.x, accB[0].x); accB[0].y = fmaf(a0, b1.y, accB[0].y);
            accB[0].z = fmaf(a0, b1.z, accB[0].z); accB[0].w = fmaf(a0, b1.w, accB[0].w);
            accA[1].x = fmaf(a1, b0.x, accA[1].x); accA[1].y = fmaf(a1, b0.y, accA[1].y);
            accA[1].z = fmaf(a1, b0.z, accA[1].z); accA[1].w = fmaf(a1, b0.w, accA[1].w);
            accB[1].x = fmaf(a1, b1.x, accB[1].x); accB[1].y = fmaf(a1, b1.y, accB[1].y);
            accB[1].z = fmaf(a1, b1.z, accB[1].z); accB[1].w = fmaf(a1, b1.w, accB[1].w);
        }
        __syncthreads();
    }
#pragma unroll
    for (int r = 0; r < 2; r++) {
        int row = row0 + ty * 2 + r;
        float dv = dinv[row];
        float4 oA = accA[r], oB = accB[r];
        oA.x *= dv; oA.y *= dv; oA.z *= dv; oA.w *= dv;
        oB.x *= dv; oB.y *= dv; oB.z *= dv; oB.w *= dv;
        *(float4*)&C[(size_t)row * 128 + tx * 4] = oA;
        *(float4*)&C[(size_t)row * 128 + 64 + tx * 4] = oB;
    }
}

// ------------- aggregation: out[v] = relu(dinv[v]*(sum_{s in N(v)} ts[s] + ts[v]) + b)
// ts rows are already pre-scaled by dinv[src] (GEMM epilogue). One wave per node.
__global__ __launch_bounds__(256) void k_aggregate(const float* __restrict__ ts,
                                                   const int* __restrict__ offsets,
                                                   const int* __restrict__ csr_src,
                                                   const float* __restrict__ dinv,
                                                   const float* __restrict__ bias,
                                                   float* __restrict__ out) {
    int node = blockIdx.x * 4 + (threadIdx.x >> 6);
    if (node >= GN) return;
    int lane = threadIdx.x & 63;
    const float2* t2 = (const float2*)ts;
    int beg = offsets[node];
    int end = offsets[node + 1];
    float di = dinv[node];
    float ax = 0.f, ay = 0.f;
    int j = beg;
    for (; j + 8 <= end; j += 8) {
        int s0 = csr_src[j + 0], s1 = csr_src[j + 1], s2 = csr_src[j + 2], s3 = csr_src[j + 3];
        int s4 = csr_src[j + 4], s5 = csr_src[j + 5], s6 = csr_src[j + 6], s7 = csr_src[j + 7];
        float2 v0 = t2[s0 * 64 + lane], v1 = t2[s1 * 64 + lane];
        float2 v2 = t2[s2 * 64 + lane], v3 = t2[s3 * 64 + lane];
        float2 v4 = t2[s4 * 64 + lane], v5 = t2[s5 * 64 + lane];
        float2 v6 = t2[s6 * 64 + lane], v7 = t2[s7 * 64 + lane];
        ax += ((v0.x + v1.x) + (v2.x + v3.x)) + ((v4.x + v5.x) + (v6.x + v7.x));
        ay += ((v0.y + v1.y) + (v2.y + v3.y)) + ((v4.y + v5.y) + (v6.y + v7.y));
    }
    for (; j < end; j++) {
        int s = csr_src[j];
        float2 v = t2[s * 64 + lane];
        ax += v.x; ay += v.y;
    }
    float2 sv = t2[node * 64 + lane];  // self-loop term (pre-scaled by dinv[node])
    float bx = bias[lane * 2 + 0], by = bias[lane * 2 + 1];
    float ox = fmaf(di, ax + sv.x, bx);
    float oy = fmaf(di, ay + sv.y, by);
    ox = fmaxf(ox, 0.f);
    oy = fmaxf(oy, 0.f);
    float2 o = {ox, oy};
    ((float2*)out)[(size_t)node * 64 + lane] = o;
}

// ------------- mean pool per graph (batch sorted) -------------
__global__ void k_pool(const float* __restrict__ h, const int* __restrict__ batch,
                       float* __restrict__ pooled) {
    int g = blockIdx.x;
    int t = threadIdx.x;
    int f = t & 127, half = t >> 7;
    // lower bound
    int lo = 0, hi = GN;
    while (lo < hi) { int m = (lo + hi) >> 1; if (batch[m] < g) lo = m + 1; else hi = m; }
    int start = lo;
    hi = GN;
    while (lo < hi) { int m = (lo + hi) >> 1; if (batch[m] <= g) lo = m + 1; else hi = m; }
    int end = lo;
    float a0 = 0.f, a1 = 0.f, a2 = 0.f, a3 = 0.f;
    int i = start + half;
    for (; i + 6 < end; i += 8) {
        a0 += h[(size_t)(i + 0) * 128 + f];
        a1 += h[(size_t)(i + 2) * 128 + f];
        a2 += h[(size_t)(i + 4) * 128 + f];
        a3 += h[(size_t)(i + 6) * 128 + f];
    }
    for (; i < end; i += 2) a0 += h[(size_t)i * 128 + f];
    float s = (a0 + a1) + (a2 + a3);
    __shared__ float red[256];
    red[t] = s;
    __syncthreads();
    if (t < 128) {
        float tot = red[t] + red[t + 128];
        pooled[g * 128 + f] = tot / fmaxf((float)(end - start), 1.0f);
    }
}

// ------------- value head: v = tanh(pooled @ Wv + bv) -------------
__global__ void k_value(const float* __restrict__ pooled, const float* __restrict__ Wv,
                        const float* __restrict__ bv, float* __restrict__ out) {
    int g = threadIdx.x;  // 256 threads, 1 block
    const float4* p4 = (const float4*)(pooled + g * 128);
    const float4* w4 = (const float4*)Wv;
    float s = 0.f;
#pragma unroll 8
    for (int i = 0; i < 32; i++) {
        float4 a = p4[i], b = w4[i];
        s += a.x * b.x + a.y * b.y + a.z * b.z + a.w * b.w;
    }
    out[g] = tanhf(s + bv[0]);
}

// ------------- policy head: p = softmax(pooled @ Wp + bp) -------------
__global__ __launch_bounds__(256) void k_policy(const float* __restrict__ pooled,
                                                const float* __restrict__ Wp,
                                                const float* __restrict__ bp,
                                                float* __restrict__ out) {
    int g = blockIdx.x;
    int t = threadIdx.x;
    __shared__ float pr[128];
    __shared__ float red[256];
    if (t < 128) pr[t] = pooled[g * 128 + t];
    __syncthreads();
    float acc0 = bp[t + 0], acc1 = bp[t + 256], acc2 = bp[t + 512], acc3 = bp[t + 768];
    for (int k = 0; k < 128; k++) {
        float pv = pr[k];
        const float* wr = Wp + (size_t)k * 1024;
        acc0 = fmaf(pv, wr[t + 0],   acc0);
        acc1 = fmaf(pv, wr[t + 256], acc1);
        acc2 = fmaf(pv, wr[t + 512], acc2);
        acc3 = fmaf(pv, wr[t + 768], acc3);
    }
    float m = fmaxf(fmaxf(acc0, acc1), fmaxf(acc2, acc3));
    red[t] = m;
    __syncthreads();
    for (int off = 128; off > 0; off >>= 1) {
        if (t < off) red[t] = fmaxf(red[t], red[t + off]);
        __syncthreads();
    }
    float mx = red[0];
    __syncthreads();
    float e0 = __expf(acc0 - mx), e1 = __expf(acc1 - mx);
    float e2 = __expf(acc2 - mx), e3 = __expf(acc3 - mx);
    red[t] = (e0 + e1) + (e2 + e3);
    __syncthreads();
    for (int off = 128; off > 0; off >>= 1) {
        if (t < off) red[t] += red[t + off];
        __syncthreads();
    }
    float inv = 1.0f / red[0];
    out[(size_t)g * 1024 + t + 0]   = e0 * inv;
    out[(size_t)g * 1024 + t + 256] = e1 * inv;
    out[(size_t)g * 1024 + t + 512] = e2 * inv;
    out[(size_t)g * 1024 + t + 768] = e3 * inv;
}

extern "C" void kernel_launch(void* const* d_in, const int* in_sizes, int n_in,
                              void* d_out, int out_size, void* d_ws, size_t ws_size,
                              hipStream_t stream) {
    const float* x    = (const float*)d_in[0];
    const int*   ei   = (const int*)d_in[1];
    const int*   srcA = ei;        // edge_index[0]
    const int*   dstA = ei + GE;   // edge_index[1]
    const int*   batch = (const int*)d_in[2];
    const float* W1 = (const float*)d_in[3];
    const float* b1 = (const float*)d_in[4];
    const float* W2 = (const float*)d_in[5];
    const float* b2 = (const float*)d_in[6];
    const float* Wv = (const float*)d_in[7];
    const float* bv = (const float*)d_in[8];
    const float* Wp = (const float*)d_in[9];
    const float* bp = (const float*)d_in[10];
    float* out = (float*)d_out;

    char* ws = (char*)d_ws;
    float* bufA = (float*)ws;              ws += (size_t)GN * 128 * 4;  // 51.2 MB
    float* bufB = (float*)ws;              ws += (size_t)GN * 128 * 4;  // 51.2 MB
    float* pooled = (float*)ws;            ws += (size_t)GB * 128 * 4;
    float* dinv = (float*)ws;              ws += (size_t)GN * 4;
    int*   deg = (int*)ws;                 ws += (size_t)GN * 4;
    int*   cursor = (int*)ws;              ws += (size_t)GN * 4;
    int*   csr_src = (int*)ws;             ws += (size_t)GE * 4;
    int*   bsum = (int*)ws;                ws += 512;
    int*   offsets = (int*)ws;             ws += (size_t)(GN + 1) * 4;

    // --- CSR build ---
    hipMemsetAsync(deg, 0, (size_t)GN * 4, stream);
    k_count<<<(GE + 255) / 256, 256, 0, stream>>>(dstA, deg);
    int nb = (GN + 1023) / 1024;  // 98
    k_scan1<<<nb, 256, 0, stream>>>(deg, offsets, bsum);
    k_scan2<<<1, 128, 0, stream>>>(bsum, nb);
    k_scan3<<<(GN + 255) / 256, 256, 0, stream>>>(bsum, deg, offsets, cursor, dinv);
    k_scatter<<<(GE + 255) / 256, 256, 0, stream>>>(srcA, dstA, cursor, csr_src);

    // --- layer 1: ts = dinv .* (x @ W1); h1 = relu(dinv*(gather-sum + self) + b1) ---
    k_gemm<<<GN / 32, 256, 0, stream>>>(x, W1, dinv, bufA);
    k_aggregate<<<GN / 4, 256, 0, stream>>>(bufA, offsets, csr_src, dinv, b1, bufB);

    // --- layer 2 ---
    k_gemm<<<GN / 32, 256, 0, stream>>>(bufB, W2, dinv, bufA);
    k_aggregate<<<GN / 4, 256, 0, stream>>>(bufA, offsets, csr_src, dinv, b2, bufB);

    // --- pool + heads ---
    k_pool<<<GB, 256, 0, stream>>>(bufB, batch, pooled);
    k_value<<<1, 256, 0, stream>>>(pooled, Wv, bv, out);
    k_policy<<<GB, 256, 0, stream>>>(pooled, Wp, bp, out + GB);
}

// Round 3
// 796.500 us; speedup vs baseline: 1.2640x; 1.2640x over previous
//
#include <hip/hip_runtime.h>
#include <hip/hip_bf16.h>

#define GN 100000   // nodes
#define GE 3200000  // edges
#define GH 128      // feature/hidden width
#define GA 1024     // actions
#define GB 256      // graphs

#define NBUK 391    // ceil(GN / 256) buckets of 256 nodes
#define CPAD 16     // counter padding (ints) -> one 64B line per counter
#define SBLK 2048   // scatter/hist blocks (identical partition for both!)
#define SCHUNK 1563 // ceil(GE / SBLK)

// ---------------- CSR build via XCD-local bucket binning ----------------
// CRITICAL: k_hist and k_binscatter must use the SAME edge->block partition and
// the SAME bno = blockIdx&7, so each (bucket,bno) sub-region's scatter count
// exactly equals its histogram count (no overflow, no unwritten slots).

__global__ __launch_bounds__(256) void k_hist(const int* __restrict__ dst,
                                              int* __restrict__ bkt_cnt) {
    __shared__ int hist[NBUK];
    int t = threadIdx.x;
    for (int i = t; i < NBUK; i += 256) hist[i] = 0;
    __syncthreads();
    int bno = blockIdx.x & 7;
    int beg = blockIdx.x * SCHUNK;
    int end = beg + SCHUNK; if (end > GE) end = GE;
    for (int e = beg + t; e < end; e += 256)
        atomicAdd(&hist[dst[e] >> 8], 1);
    __syncthreads();
    for (int i = t; i < NBUK; i += 256) {
        int c = hist[i];
        if (c) atomicAdd(&bkt_cnt[(i * 8 + bno) * CPAD], c);
    }
}

// exclusive scan of the 3128 (bucket,xcd) counts -> sub-region bases
__global__ __launch_bounds__(1024) void k_scan_bkt(const int* __restrict__ bkt_cnt,
                                                   int* __restrict__ bkt_cursor,
                                                   int* __restrict__ bucket_base,
                                                   int* __restrict__ offsets) {
    int t = threadIdx.x;
    int v[4]; int s = 0;
#pragma unroll
    for (int i = 0; i < 4; i++) {
        int idx = t * 4 + i;
        v[i] = (idx < NBUK * 8) ? bkt_cnt[idx * CPAD] : 0;
        s += v[i];
    }
    int lane = t & 63, w = t >> 6;
    int x = s;
#pragma unroll
    for (int off = 1; off < 64; off <<= 1) {
        int y = __shfl_up(x, off);
        if (lane >= off) x += y;
    }
    __shared__ int wsc[16];
    if (lane == 63) wsc[w] = x;
    __syncthreads();
    int wo = 0;
#pragma unroll
    for (int i = 0; i < 16; i++)
        if (i < w) wo += wsc[i];
    int excl = wo + x - s;
#pragma unroll
    for (int i = 0; i < 4; i++) {
        int idx = t * 4 + i;
        if (idx < NBUK * 8) {
            bkt_cursor[idx * CPAD] = excl;
            if ((idx & 7) == 0) bucket_base[idx >> 3] = excl;
        }
        excl += v[i];
    }
    if (t == 0) offsets[GN] = GE;
}

// scatter edges into per-(bucket,bno) sub-regions; packed 4B entries
__global__ __launch_bounds__(256) void k_binscatter(const int* __restrict__ src,
                                                    const int* __restrict__ dst,
                                                    int* __restrict__ bkt_cursor,
                                                    unsigned int* __restrict__ binned) {
    int t = threadIdx.x;
    int bno = blockIdx.x & 7;
    int beg = blockIdx.x * SCHUNK;
    int end = beg + SCHUNK; if (end > GE) end = GE;
    for (int e = beg + t; e < end; e += 256) {
        int d = dst[e];
        int buk = d >> 8;
        int pos = atomicAdd(&bkt_cursor[(buk * 8 + bno) * CPAD], 1);
        binned[pos] = (unsigned int)src[e] | ((unsigned int)(d & 255) << 17);
    }
}

// one block per bucket: LDS counting sort to node granularity -> CSR + deg/dinv
__global__ __launch_bounds__(256) void k_bucket_sort(const unsigned int* __restrict__ binned,
                                                     const int* __restrict__ bucket_base,
                                                     int* __restrict__ csr_src,
                                                     int* __restrict__ offsets,
                                                     float* __restrict__ dinv) {
    int buk = blockIdx.x;
    int t = threadIdx.x;
    __shared__ int hist[256];
    __shared__ int cur[256];
    __shared__ int wsum[4];
    hist[t] = 0;
    __syncthreads();
    int beg = bucket_base[buk];
    int end = (buk + 1 < NBUK) ? bucket_base[buk + 1] : GE;
    for (int e = beg + t; e < end; e += 256)
        atomicAdd(&hist[(binned[e] >> 17) & 255], 1);
    __syncthreads();
    int h = hist[t];
    int lane = t & 63, w = t >> 6;
    int x = h;
#pragma unroll
    for (int off = 1; off < 64; off <<= 1) {
        int y = __shfl_up(x, off);
        if (lane >= off) x += y;
    }
    if (lane == 63) wsum[w] = x;
    __syncthreads();
    int wo = 0;
#pragma unroll
    for (int i = 0; i < 4; i++)
        if (i < w) wo += wsum[i];
    int excl = wo + x - h;  // exclusive prefix over local nodes
    int node = (buk << 8) + t;
    if (node < GN) {
        offsets[node] = beg + excl;
        dinv[node] = rsqrtf((float)(h + 1));  // +1 self-loop
    }
    cur[t] = excl;
    __syncthreads();
    for (int e = beg + t; e < end; e += 256) {
        unsigned int v = binned[e];
        int dl = (v >> 17) & 255;
        int p = atomicAdd(&cur[dl], 1);
        csr_src[beg + p] = (int)(v & 0x1FFFF);
    }
}

// ---------------- GEMM: C[row] = dinv[row] * (A[row] @ W), A:[GN,128] W:[128,128]
__global__ __launch_bounds__(256) void k_gemm(const float* __restrict__ A,
                                              const float* __restrict__ W,
                                              const float* __restrict__ dinv,
                                              float* __restrict__ C) {
    __shared__ float Ws[64][128];
    __shared__ float As[32][68];
    int t = threadIdx.x;
    int ty = t >> 4, tx = t & 15;
    int row0 = blockIdx.x * 32;

    float4 accA[2] = {{0, 0, 0, 0}, {0, 0, 0, 0}};
    float4 accB[2] = {{0, 0, 0, 0}, {0, 0, 0, 0}};

    for (int kb = 0; kb < 128; kb += 64) {
#pragma unroll
        for (int i = 0; i < 8; i++) {
            int q = t + 256 * i;
            int kr = q >> 5;
            int c4 = (q & 31) << 2;
            *(float4*)&Ws[kr][c4] = *(const float4*)&W[(kb + kr) * 128 + c4];
        }
#pragma unroll
        for (int i = 0; i < 2; i++) {
            int q = t + 256 * i;
            int ar = q >> 4;
            int c4 = (q & 15) << 2;
            *(float4*)&As[ar][c4] = *(const float4*)&A[(size_t)(row0 + ar) * 128 + kb + c4];
        }
        __syncthreads();
#pragma unroll 8
        for (int k = 0; k < 64; k++) {
            float a0 = As[ty * 2 + 0][k];
            float a1 = As[ty * 2 + 1][k];
            float4 b0 = *(float4*)&Ws[k][tx * 4];
            float4 b1 = *(float4*)&Ws[k][64 + tx * 4];
            accA[0].x = fmaf(a0, b0.x, accA[0].x); accA[0].y = fmaf(a0, b0.y, accA[0].y);
            accA[0].z = fmaf(a0, b0.z, accA[0].z); accA[0].w = fmaf(a0, b0.w, accA[0].w);
            accB[0].x = fmaf(a0, b1.x, accB[0].x); accB[0].y = fmaf(a0, b1.y, accB[0].y);
            accB[0].z = fmaf(a0, b1.z, accB[0].z); accB[0].w = fmaf(a0, b1.w, accB[0].w);
            accA[1].x = fmaf(a1, b0.x, accA[1].x); accA[1].y = fmaf(a1, b0.y, accA[1].y);
            accA[1].z = fmaf(a1, b0.z, accA[1].z); accA[1].w = fmaf(a1, b0.w, accA[1].w);
            accB[1].x = fmaf(a1, b1.x, accB[1].x); accB[1].y = fmaf(a1, b1.y, accB[1].y);
            accB[1].z = fmaf(a1, b1.z, accB[1].z); accB[1].w = fmaf(a1, b1.w, accB[1].w);
        }
        __syncthreads();
    }
#pragma unroll
    for (int r = 0; r < 2; r++) {
        int row = row0 + ty * 2 + r;
        float dv = dinv[row];
        float4 oA = accA[r], oB = accB[r];
        oA.x *= dv; oA.y *= dv; oA.z *= dv; oA.w *= dv;
        oB.x *= dv; oB.y *= dv; oB.z *= dv; oB.w *= dv;
        *(float4*)&C[(size_t)row * 128 + tx * 4] = oA;
        *(float4*)&C[(size_t)row * 128 + 64 + tx * 4] = oB;
    }
}

// ------------- aggregation: out[v] = relu(dinv[v]*(sum ts[src] + ts[v]) + b) -------------
__global__ __launch_bounds__(256) void k_aggregate(const float* __restrict__ ts,
                                                   const int* __restrict__ offsets,
                                                   const int* __restrict__ csr_src,
                                                   const float* __restrict__ dinv,
                                                   const float* __restrict__ bias,
                                                   float* __restrict__ out) {
    int node = blockIdx.x * 4 + (threadIdx.x >> 6);
    if (node >= GN) return;
    int lane = threadIdx.x & 63;
    const float2* t2 = (const float2*)ts;
    int beg = offsets[node];
    int end = offsets[node + 1];
    float di = dinv[node];
    float ax = 0.f, ay = 0.f;
    int j = beg;
    for (; j + 8 <= end; j += 8) {
        int s0 = csr_src[j + 0], s1 = csr_src[j + 1], s2 = csr_src[j + 2], s3 = csr_src[j + 3];
        int s4 = csr_src[j + 4], s5 = csr_src[j + 5], s6 = csr_src[j + 6], s7 = csr_src[j + 7];
        float2 v0 = t2[s0 * 64 + lane], v1 = t2[s1 * 64 + lane];
        float2 v2 = t2[s2 * 64 + lane], v3 = t2[s3 * 64 + lane];
        float2 v4 = t2[s4 * 64 + lane], v5 = t2[s5 * 64 + lane];
        float2 v6 = t2[s6 * 64 + lane], v7 = t2[s7 * 64 + lane];
        ax += ((v0.x + v1.x) + (v2.x + v3.x)) + ((v4.x + v5.x) + (v6.x + v7.x));
        ay += ((v0.y + v1.y) + (v2.y + v3.y)) + ((v4.y + v5.y) + (v6.y + v7.y));
    }
    for (; j < end; j++) {
        int s = csr_src[j];
        float2 v = t2[s * 64 + lane];
        ax += v.x; ay += v.y;
    }
    float2 sv = t2[node * 64 + lane];
    float bx = bias[lane * 2 + 0], by = bias[lane * 2 + 1];
    float ox = fmaf(di, ax + sv.x, bx);
    float oy = fmaf(di, ay + sv.y, by);
    ox = fmaxf(ox, 0.f);
    oy = fmaxf(oy, 0.f);
    float2 o = {ox, oy};
    ((float2*)out)[(size_t)node * 64 + lane] = o;
}

// ------------- mean pool per graph (batch sorted) -------------
__global__ void k_pool(const float* __restrict__ h, const int* __restrict__ batch,
                       float* __restrict__ pooled) {
    int g = blockIdx.x;
    int t = threadIdx.x;
    int f = t & 127, half = t >> 7;
    int lo = 0, hi = GN;
    while (lo < hi) { int m = (lo + hi) >> 1; if (batch[m] < g) lo = m + 1; else hi = m; }
    int start = lo;
    hi = GN;
    while (lo < hi) { int m = (lo + hi) >> 1; if (batch[m] <= g) lo = m + 1; else hi = m; }
    int end = lo;
    float a0 = 0.f, a1 = 0.f, a2 = 0.f, a3 = 0.f;
    int i = start + half;
    for (; i + 6 < end; i += 8) {
        a0 += h[(size_t)(i + 0) * 128 + f];
        a1 += h[(size_t)(i + 2) * 128 + f];
        a2 += h[(size_t)(i + 4) * 128 + f];
        a3 += h[(size_t)(i + 6) * 128 + f];
    }
    for (; i < end; i += 2) a0 += h[(size_t)i * 128 + f];
    float s = (a0 + a1) + (a2 + a3);
    __shared__ float red[256];
    red[t] = s;
    __syncthreads();
    if (t < 128) {
        float tot = red[t] + red[t + 128];
        pooled[g * 128 + f] = tot / fmaxf((float)(end - start), 1.0f);
    }
}

// ------------- value head -------------
__global__ void k_value(const float* __restrict__ pooled, const float* __restrict__ Wv,
                        const float* __restrict__ bv, float* __restrict__ out) {
    int g = threadIdx.x;
    const float4* p4 = (const float4*)(pooled + g * 128);
    const float4* w4 = (const float4*)Wv;
    float s = 0.f;
#pragma unroll 8
    for (int i = 0; i < 32; i++) {
        float4 a = p4[i], b = w4[i];
        s += a.x * b.x + a.y * b.y + a.z * b.z + a.w * b.w;
    }
    out[g] = tanhf(s + bv[0]);
}

// ------------- policy head -------------
__global__ __launch_bounds__(256) void k_policy(const float* __restrict__ pooled,
                                                const float* __restrict__ Wp,
                                                const float* __restrict__ bp,
                                                float* __restrict__ out) {
    int g = blockIdx.x;
    int t = threadIdx.x;
    __shared__ float pr[128];
    __shared__ float red[256];
    if (t < 128) pr[t] = pooled[g * 128 + t];
    __syncthreads();
    float acc0 = bp[t + 0], acc1 = bp[t + 256], acc2 = bp[t + 512], acc3 = bp[t + 768];
    for (int k = 0; k < 128; k++) {
        float pv = pr[k];
        const float* wr = Wp + (size_t)k * 1024;
        acc0 = fmaf(pv, wr[t + 0],   acc0);
        acc1 = fmaf(pv, wr[t + 256], acc1);
        acc2 = fmaf(pv, wr[t + 512], acc2);
        acc3 = fmaf(pv, wr[t + 768], acc3);
    }
    float m = fmaxf(fmaxf(acc0, acc1), fmaxf(acc2, acc3));
    red[t] = m;
    __syncthreads();
    for (int off = 128; off > 0; off >>= 1) {
        if (t < off) red[t] = fmaxf(red[t], red[t + off]);
        __syncthreads();
    }
    float mx = red[0];
    __syncthreads();
    float e0 = __expf(acc0 - mx), e1 = __expf(acc1 - mx);
    float e2 = __expf(acc2 - mx), e3 = __expf(acc3 - mx);
    red[t] = (e0 + e1) + (e2 + e3);
    __syncthreads();
    for (int off = 128; off > 0; off >>= 1) {
        if (t < off) red[t] += red[t + off];
        __syncthreads();
    }
    float inv = 1.0f / red[0];
    out[(size_t)g * 1024 + t + 0]   = e0 * inv;
    out[(size_t)g * 1024 + t + 256] = e1 * inv;
    out[(size_t)g * 1024 + t + 512] = e2 * inv;
    out[(size_t)g * 1024 + t + 768] = e3 * inv;
}

extern "C" void kernel_launch(void* const* d_in, const int* in_sizes, int n_in,
                              void* d_out, int out_size, void* d_ws, size_t ws_size,
                              hipStream_t stream) {
    const float* x    = (const float*)d_in[0];
    const int*   ei   = (const int*)d_in[1];
    const int*   srcA = ei;        // edge_index[0]
    const int*   dstA = ei + GE;   // edge_index[1]
    const int*   batch = (const int*)d_in[2];
    const float* W1 = (const float*)d_in[3];
    const float* b1 = (const float*)d_in[4];
    const float* W2 = (const float*)d_in[5];
    const float* b2 = (const float*)d_in[6];
    const float* Wv = (const float*)d_in[7];
    const float* bv = (const float*)d_in[8];
    const float* Wp = (const float*)d_in[9];
    const float* bp = (const float*)d_in[10];
    float* out = (float*)d_out;

    char* ws = (char*)d_ws;
    float* bufA = (float*)ws;        ws += (size_t)GN * 128 * 4;  // 51.2 MB
    float* bufB = (float*)ws;        ws += (size_t)GN * 128 * 4;  // 51.2 MB
    float* pooled = (float*)ws;      ws += (size_t)GB * 128 * 4;
    float* dinv = (float*)ws;        ws += (size_t)100032 * 4;
    int*   csr_src = (int*)ws;       ws += (size_t)GE * 4;        // 12.8 MB
    int*   offsets = (int*)ws;       ws += (size_t)100032 * 4;
    int*   bkt_cnt = (int*)ws;       ws += (size_t)NBUK * 8 * CPAD * 4;
    int*   bkt_cursor = (int*)ws;    ws += (size_t)NBUK * 8 * CPAD * 4;
    int*   bucket_base = (int*)ws;   ws += 448 * 4;
    unsigned int* binned = (unsigned int*)bufA;  // alias: consumed before first k_gemm

    // --- CSR build (bucketed, XCD-local write streams) ---
    hipMemsetAsync(bkt_cnt, 0, (size_t)NBUK * 8 * CPAD * 4, stream);
    k_hist<<<SBLK, 256, 0, stream>>>(dstA, bkt_cnt);
    k_scan_bkt<<<1, 1024, 0, stream>>>(bkt_cnt, bkt_cursor, bucket_base, offsets);
    k_binscatter<<<SBLK, 256, 0, stream>>>(srcA, dstA, bkt_cursor, binned);
    k_bucket_sort<<<NBUK, 256, 0, stream>>>(binned, bucket_base, csr_src, offsets, dinv);

    // --- layer 1 ---
    k_gemm<<<GN / 32, 256, 0, stream>>>(x, W1, dinv, bufA);
    k_aggregate<<<GN / 4, 256, 0, stream>>>(bufA, offsets, csr_src, dinv, b1, bufB);

    // --- layer 2 ---
    k_gemm<<<GN / 32, 256, 0, stream>>>(bufB, W2, dinv, bufA);
    k_aggregate<<<GN / 4, 256, 0, stream>>>(bufA, offsets, csr_src, dinv, b2, bufB);

    // --- pool + heads ---
    k_pool<<<GB, 256, 0, stream>>>(bufB, batch, pooled);
    k_value<<<1, 256, 0, stream>>>(pooled, Wv, bv, out);
    k_policy<<<GB, 256, 0, stream>>>(pooled, Wp, bp, out + GB);
}

// Round 4
// 611.976 us; speedup vs baseline: 1.6451x; 1.3015x over previous
//
#include <hip/hip_runtime.h>
#include <hip/hip_bf16.h>

#define GN 100000   // nodes
#define GE 3200000  // edges
#define GH 128      // feature/hidden width
#define GA 1024     // actions
#define GB 256      // graphs

#define NBUK 391    // ceil(GN / 256) buckets of 256 nodes
#define CPAD 16     // counter padding (ints) -> one 64B line per counter
#define SBLK 2048   // scatter/hist blocks (identical partition for both!)
#define SCHUNK 1563 // ceil(GE / SBLK)

// round-to-nearest-even fp32 -> bf16 (as ushort)
__device__ __forceinline__ unsigned int f2bf(float f) {
    unsigned int u = __float_as_uint(f);
    return (u + 0x7fffu + ((u >> 16) & 1u)) >> 16;
}

// ---------------- CSR build via XCD-local bucket binning ----------------
// CRITICAL: k_hist and k_binscatter use the SAME edge->block partition and
// the SAME bno = blockIdx&7, so each (bucket,bno) sub-region's scatter count
// exactly equals its histogram count (no overflow, no unwritten slots).

__global__ __launch_bounds__(256) void k_hist(const int* __restrict__ dst,
                                              int* __restrict__ bkt_cnt) {
    __shared__ int hist[NBUK];
    int t = threadIdx.x;
    for (int i = t; i < NBUK; i += 256) hist[i] = 0;
    __syncthreads();
    int bno = blockIdx.x & 7;
    int beg = blockIdx.x * SCHUNK;
    int end = beg + SCHUNK; if (end > GE) end = GE;
    for (int e = beg + t; e < end; e += 256)
        atomicAdd(&hist[dst[e] >> 8], 1);
    __syncthreads();
    for (int i = t; i < NBUK; i += 256) {
        int c = hist[i];
        if (c) atomicAdd(&bkt_cnt[(i * 8 + bno) * CPAD], c);
    }
}

__global__ __launch_bounds__(1024) void k_scan_bkt(const int* __restrict__ bkt_cnt,
                                                   int* __restrict__ bkt_cursor,
                                                   int* __restrict__ bucket_base,
                                                   int* __restrict__ offsets) {
    int t = threadIdx.x;
    int v[4]; int s = 0;
#pragma unroll
    for (int i = 0; i < 4; i++) {
        int idx = t * 4 + i;
        v[i] = (idx < NBUK * 8) ? bkt_cnt[idx * CPAD] : 0;
        s += v[i];
    }
    int lane = t & 63, w = t >> 6;
    int x = s;
#pragma unroll
    for (int off = 1; off < 64; off <<= 1) {
        int y = __shfl_up(x, off);
        if (lane >= off) x += y;
    }
    __shared__ int wsc[16];
    if (lane == 63) wsc[w] = x;
    __syncthreads();
    int wo = 0;
#pragma unroll
    for (int i = 0; i < 16; i++)
        if (i < w) wo += wsc[i];
    int excl = wo + x - s;
#pragma unroll
    for (int i = 0; i < 4; i++) {
        int idx = t * 4 + i;
        if (idx < NBUK * 8) {
            bkt_cursor[idx * CPAD] = excl;
            if ((idx & 7) == 0) bucket_base[idx >> 3] = excl;
        }
        excl += v[i];
    }
    if (t == 0) offsets[GN] = GE;
}

__global__ __launch_bounds__(256) void k_binscatter(const int* __restrict__ src,
                                                    const int* __restrict__ dst,
                                                    int* __restrict__ bkt_cursor,
                                                    unsigned int* __restrict__ binned) {
    int t = threadIdx.x;
    int bno = blockIdx.x & 7;
    int beg = blockIdx.x * SCHUNK;
    int end = beg + SCHUNK; if (end > GE) end = GE;
    for (int e = beg + t; e < end; e += 256) {
        int d = dst[e];
        int buk = d >> 8;
        int pos = atomicAdd(&bkt_cursor[(buk * 8 + bno) * CPAD], 1);
        binned[pos] = (unsigned int)src[e] | ((unsigned int)(d & 255) << 17);
    }
}

__global__ __launch_bounds__(256) void k_bucket_sort(const unsigned int* __restrict__ binned,
                                                     const int* __restrict__ bucket_base,
                                                     int* __restrict__ csr_src,
                                                     int* __restrict__ offsets,
                                                     float* __restrict__ dinv) {
    int buk = blockIdx.x;
    int t = threadIdx.x;
    __shared__ int hist[256];
    __shared__ int cur[256];
    __shared__ int wsum[4];
    hist[t] = 0;
    __syncthreads();
    int beg = bucket_base[buk];
    int end = (buk + 1 < NBUK) ? bucket_base[buk + 1] : GE;
    for (int e = beg + t; e < end; e += 256)
        atomicAdd(&hist[(binned[e] >> 17) & 255], 1);
    __syncthreads();
    int h = hist[t];
    int lane = t & 63, w = t >> 6;
    int x = h;
#pragma unroll
    for (int off = 1; off < 64; off <<= 1) {
        int y = __shfl_up(x, off);
        if (lane >= off) x += y;
    }
    if (lane == 63) wsum[w] = x;
    __syncthreads();
    int wo = 0;
#pragma unroll
    for (int i = 0; i < 4; i++)
        if (i < w) wo += wsum[i];
    int excl = wo + x - h;
    int node = (buk << 8) + t;
    if (node < GN) {
        offsets[node] = beg + excl;
        dinv[node] = rsqrtf((float)(h + 1));  // +1 self-loop
    }
    cur[t] = excl;
    __syncthreads();
    for (int e = beg + t; e < end; e += 256) {
        unsigned int v = binned[e];
        int dl = (v >> 17) & 255;
        int p = atomicAdd(&cur[dl], 1);
        csr_src[beg + p] = (int)(v & 0x1FFFF);
    }
}

// ---------------- GEMM: C[row] = bf16(dinv[row] * (A[row] @ W)), A fp32, C bf16 packed
__global__ __launch_bounds__(256) void k_gemm(const float* __restrict__ A,
                                              const float* __restrict__ W,
                                              const float* __restrict__ dinv,
                                              unsigned int* __restrict__ C) {
    __shared__ float Ws[64][128];
    __shared__ float As[32][68];
    int t = threadIdx.x;
    int ty = t >> 4, tx = t & 15;
    int row0 = blockIdx.x * 32;

    float4 accA[2] = {{0, 0, 0, 0}, {0, 0, 0, 0}};
    float4 accB[2] = {{0, 0, 0, 0}, {0, 0, 0, 0}};

    for (int kb = 0; kb < 128; kb += 64) {
#pragma unroll
        for (int i = 0; i < 8; i++) {
            int q = t + 256 * i;
            int kr = q >> 5;
            int c4 = (q & 31) << 2;
            *(float4*)&Ws[kr][c4] = *(const float4*)&W[(kb + kr) * 128 + c4];
        }
#pragma unroll
        for (int i = 0; i < 2; i++) {
            int q = t + 256 * i;
            int ar = q >> 4;
            int c4 = (q & 15) << 2;
            *(float4*)&As[ar][c4] = *(const float4*)&A[(size_t)(row0 + ar) * 128 + kb + c4];
        }
        __syncthreads();
#pragma unroll 8
        for (int k = 0; k < 64; k++) {
            float a0 = As[ty * 2 + 0][k];
            float a1 = As[ty * 2 + 1][k];
            float4 b0 = *(float4*)&Ws[k][tx * 4];
            float4 b1 = *(float4*)&Ws[k][64 + tx * 4];
            accA[0].x = fmaf(a0, b0.x, accA[0].x); accA[0].y = fmaf(a0, b0.y, accA[0].y);
            accA[0].z = fmaf(a0, b0.z, accA[0].z); accA[0].w = fmaf(a0, b0.w, accA[0].w);
            accB[0].x = fmaf(a0, b1.x, accB[0].x); accB[0].y = fmaf(a0, b1.y, accB[0].y);
            accB[0].z = fmaf(a0, b1.z, accB[0].z); accB[0].w = fmaf(a0, b1.w, accB[0].w);
            accA[1].x = fmaf(a1, b0.x, accA[1].x); accA[1].y = fmaf(a1, b0.y, accA[1].y);
            accA[1].z = fmaf(a1, b0.z, accA[1].z); accA[1].w = fmaf(a1, b0.w, accA[1].w);
            accB[1].x = fmaf(a1, b1.x, accB[1].x); accB[1].y = fmaf(a1, b1.y, accB[1].y);
            accB[1].z = fmaf(a1, b1.z, accB[1].z); accB[1].w = fmaf(a1, b1.w, accB[1].w);
        }
        __syncthreads();
    }
#pragma unroll
    for (int r = 0; r < 2; r++) {
        int row = row0 + ty * 2 + r;
        float dv = dinv[row];
        float4 oA = accA[r], oB = accB[r];
        uint2 pA, pB;
        pA.x = f2bf(oA.x * dv) | (f2bf(oA.y * dv) << 16);
        pA.y = f2bf(oA.z * dv) | (f2bf(oA.w * dv) << 16);
        pB.x = f2bf(oB.x * dv) | (f2bf(oB.y * dv) << 16);
        pB.y = f2bf(oB.z * dv) | (f2bf(oB.w * dv) << 16);
        // uint index: row*64 + col/2
        *(uint2*)&C[(size_t)row * 64 + tx * 2] = pA;
        *(uint2*)&C[(size_t)row * 64 + 32 + tx * 2] = pB;
    }
}

// ------------- aggregation: out[v] = relu(dinv[v]*(sum ts[src] + ts[v]) + b)
// ts rows are bf16 (pre-scaled by dinv[src]); accumulate fp32; out fp32.
__global__ __launch_bounds__(256) void k_aggregate(const unsigned int* __restrict__ ts,
                                                   const int* __restrict__ offsets,
                                                   const int* __restrict__ csr_src,
                                                   const float* __restrict__ dinv,
                                                   const float* __restrict__ bias,
                                                   float* __restrict__ out) {
    int node = blockIdx.x * 4 + (threadIdx.x >> 6);
    if (node >= GN) return;
    int lane = threadIdx.x & 63;
    int beg = offsets[node];
    int end = offsets[node + 1];
    float di = dinv[node];
    float ax = 0.f, ay = 0.f;
#define BFLO(u) __uint_as_float((u) << 16)
#define BFHI(u) __uint_as_float((u) & 0xffff0000u)
    int j = beg;
    for (; j + 8 <= end; j += 8) {
        int s0 = csr_src[j + 0], s1 = csr_src[j + 1], s2 = csr_src[j + 2], s3 = csr_src[j + 3];
        int s4 = csr_src[j + 4], s5 = csr_src[j + 5], s6 = csr_src[j + 6], s7 = csr_src[j + 7];
        unsigned int u0 = ts[s0 * 64 + lane], u1 = ts[s1 * 64 + lane];
        unsigned int u2 = ts[s2 * 64 + lane], u3 = ts[s3 * 64 + lane];
        unsigned int u4 = ts[s4 * 64 + lane], u5 = ts[s5 * 64 + lane];
        unsigned int u6 = ts[s6 * 64 + lane], u7 = ts[s7 * 64 + lane];
        ax += ((BFLO(u0) + BFLO(u1)) + (BFLO(u2) + BFLO(u3))) +
              ((BFLO(u4) + BFLO(u5)) + (BFLO(u6) + BFLO(u7)));
        ay += ((BFHI(u0) + BFHI(u1)) + (BFHI(u2) + BFHI(u3))) +
              ((BFHI(u4) + BFHI(u5)) + (BFHI(u6) + BFHI(u7)));
    }
    for (; j < end; j++) {
        int s = csr_src[j];
        unsigned int u = ts[s * 64 + lane];
        ax += BFLO(u); ay += BFHI(u);
    }
    unsigned int su = ts[node * 64 + lane];  // self-loop (pre-scaled by dinv[node])
    float bx = bias[lane * 2 + 0], by = bias[lane * 2 + 1];
    float ox = fmaf(di, ax + BFLO(su), bx);
    float oy = fmaf(di, ay + BFHI(su), by);
    ox = fmaxf(ox, 0.f);
    oy = fmaxf(oy, 0.f);
    float2 o = {ox, oy};
    ((float2*)out)[(size_t)node * 64 + lane] = o;
#undef BFLO
#undef BFHI
}

// ------------- mean pool per graph (batch sorted) -------------
__global__ void k_pool(const float* __restrict__ h, const int* __restrict__ batch,
                       float* __restrict__ pooled) {
    int g = blockIdx.x;
    int t = threadIdx.x;
    int f = t & 127, half = t >> 7;
    int lo = 0, hi = GN;
    while (lo < hi) { int m = (lo + hi) >> 1; if (batch[m] < g) lo = m + 1; else hi = m; }
    int start = lo;
    hi = GN;
    while (lo < hi) { int m = (lo + hi) >> 1; if (batch[m] <= g) lo = m + 1; else hi = m; }
    int end = lo;
    float a0 = 0.f, a1 = 0.f, a2 = 0.f, a3 = 0.f;
    int i = start + half;
    for (; i + 6 < end; i += 8) {
        a0 += h[(size_t)(i + 0) * 128 + f];
        a1 += h[(size_t)(i + 2) * 128 + f];
        a2 += h[(size_t)(i + 4) * 128 + f];
        a3 += h[(size_t)(i + 6) * 128 + f];
    }
    for (; i < end; i += 2) a0 += h[(size_t)i * 128 + f];
    float s = (a0 + a1) + (a2 + a3);
    __shared__ float red[256];
    red[t] = s;
    __syncthreads();
    if (t < 128) {
        float tot = red[t] + red[t + 128];
        pooled[g * 128 + f] = tot / fmaxf((float)(end - start), 1.0f);
    }
}

// ------------- value head -------------
__global__ void k_value(const float* __restrict__ pooled, const float* __restrict__ Wv,
                        const float* __restrict__ bv, float* __restrict__ out) {
    int g = threadIdx.x;
    const float4* p4 = (const float4*)(pooled + g * 128);
    const float4* w4 = (const float4*)Wv;
    float s = 0.f;
#pragma unroll 8
    for (int i = 0; i < 32; i++) {
        float4 a = p4[i], b = w4[i];
        s += a.x * b.x + a.y * b.y + a.z * b.z + a.w * b.w;
    }
    out[g] = tanhf(s + bv[0]);
}

// ------------- policy head -------------
__global__ __launch_bounds__(256) void k_policy(const float* __restrict__ pooled,
                                                const float* __restrict__ Wp,
                                                const float* __restrict__ bp,
                                                float* __restrict__ out) {
    int g = blockIdx.x;
    int t = threadIdx.x;
    __shared__ float pr[128];
    __shared__ float red[256];
    if (t < 128) pr[t] = pooled[g * 128 + t];
    __syncthreads();
    float acc0 = bp[t + 0], acc1 = bp[t + 256], acc2 = bp[t + 512], acc3 = bp[t + 768];
    for (int k = 0; k < 128; k++) {
        float pv = pr[k];
        const float* wr = Wp + (size_t)k * 1024;
        acc0 = fmaf(pv, wr[t + 0],   acc0);
        acc1 = fmaf(pv, wr[t + 256], acc1);
        acc2 = fmaf(pv, wr[t + 512], acc2);
        acc3 = fmaf(pv, wr[t + 768], acc3);
    }
    float m = fmaxf(fmaxf(acc0, acc1), fmaxf(acc2, acc3));
    red[t] = m;
    __syncthreads();
    for (int off = 128; off > 0; off >>= 1) {
        if (t < off) red[t] = fmaxf(red[t], red[t + off]);
        __syncthreads();
    }
    float mx = red[0];
    __syncthreads();
    float e0 = __expf(acc0 - mx), e1 = __expf(acc1 - mx);
    float e2 = __expf(acc2 - mx), e3 = __expf(acc3 - mx);
    red[t] = (e0 + e1) + (e2 + e3);
    __syncthreads();
    for (int off = 128; off > 0; off >>= 1) {
        if (t < off) red[t] += red[t + off];
        __syncthreads();
    }
    float inv = 1.0f / red[0];
    out[(size_t)g * 1024 + t + 0]   = e0 * inv;
    out[(size_t)g * 1024 + t + 256] = e1 * inv;
    out[(size_t)g * 1024 + t + 512] = e2 * inv;
    out[(size_t)g * 1024 + t + 768] = e3 * inv;
}

extern "C" void kernel_launch(void* const* d_in, const int* in_sizes, int n_in,
                              void* d_out, int out_size, void* d_ws, size_t ws_size,
                              hipStream_t stream) {
    const float* x    = (const float*)d_in[0];
    const int*   ei   = (const int*)d_in[1];
    const int*   srcA = ei;        // edge_index[0]
    const int*   dstA = ei + GE;   // edge_index[1]
    const int*   batch = (const int*)d_in[2];
    const float* W1 = (const float*)d_in[3];
    const float* b1 = (const float*)d_in[4];
    const float* W2 = (const float*)d_in[5];
    const float* b2 = (const float*)d_in[6];
    const float* Wv = (const float*)d_in[7];
    const float* bv = (const float*)d_in[8];
    const float* Wp = (const float*)d_in[9];
    const float* bp = (const float*)d_in[10];
    float* out = (float*)d_out;

    char* ws = (char*)d_ws;
    float* bufH = (float*)ws;        ws += (size_t)GN * 128 * 4;  // 51.2 MB fp32 h
    unsigned int* ts_bf = (unsigned int*)ws; ws += (size_t)GN * 64 * 4;  // 25.6 MB bf16 ts
    float* pooled = (float*)ws;      ws += (size_t)GB * 128 * 4;
    float* dinv = (float*)ws;        ws += (size_t)100032 * 4;
    int*   csr_src = (int*)ws;       ws += (size_t)GE * 4;        // 12.8 MB
    int*   offsets = (int*)ws;       ws += (size_t)100032 * 4;
    int*   bkt_cnt = (int*)ws;       ws += (size_t)NBUK * 8 * CPAD * 4;
    int*   bkt_cursor = (int*)ws;    ws += (size_t)NBUK * 8 * CPAD * 4;
    int*   bucket_base = (int*)ws;   ws += 448 * 4;
    unsigned int* binned = ts_bf;    // alias: consumed by k_bucket_sort before gemm1 writes ts

    // --- CSR build (bucketed, XCD-local write streams) ---
    hipMemsetAsync(bkt_cnt, 0, (size_t)NBUK * 8 * CPAD * 4, stream);
    k_hist<<<SBLK, 256, 0, stream>>>(dstA, bkt_cnt);
    k_scan_bkt<<<1, 1024, 0, stream>>>(bkt_cnt, bkt_cursor, bucket_base, offsets);
    k_binscatter<<<SBLK, 256, 0, stream>>>(srcA, dstA, bkt_cursor, binned);
    k_bucket_sort<<<NBUK, 256, 0, stream>>>(binned, bucket_base, csr_src, offsets, dinv);

    // --- layer 1: ts = bf16(dinv .* (x @ W1)); h1 = relu(dinv*(gather + self) + b1) ---
    k_gemm<<<GN / 32, 256, 0, stream>>>(x, W1, dinv, ts_bf);
    k_aggregate<<<GN / 4, 256, 0, stream>>>(ts_bf, offsets, csr_src, dinv, b1, bufH);

    // --- layer 2 ---
    k_gemm<<<GN / 32, 256, 0, stream>>>(bufH, W2, dinv, ts_bf);
    k_aggregate<<<GN / 4, 256, 0, stream>>>(ts_bf, offsets, csr_src, dinv, b2, bufH);

    // --- pool + heads ---
    k_pool<<<GB, 256, 0, stream>>>(bufH, batch, pooled);
    k_value<<<1, 256, 0, stream>>>(pooled, Wv, bv, out);
    k_policy<<<GB, 256, 0, stream>>>(pooled, Wp, bp, out + GB);
}

// Round 6
// 492.799 us; speedup vs baseline: 2.0430x; 1.2418x over previous
//
#include <hip/hip_runtime.h>
#include <hip/hip_bf16.h>

#define GN 100000   // nodes
#define GE 3200000  // edges
#define GH 128      // feature/hidden width
#define GA 1024     // actions
#define GB 256      // graphs

#define NB1 98      // coarse buckets of 1024 nodes (ceil(GN/1024))
#define B1BLK 5120  // edges per k_bin1 block
#define NBIN1 625   // k_bin1 blocks: 625 * 5120 = GE exactly

// round-to-nearest-even fp32 -> bf16 (as ushort)
__device__ __forceinline__ unsigned int f2bf(float f) {
    unsigned int u = __float_as_uint(f);
    return (u + 0x7fffu + ((u >> 16) & 1u)) >> 16;
}

// ---------------- CSR build: coarse bin (LDS-staged coalesced) + in-bucket sort ----

__global__ __launch_bounds__(256) void k_hist_coarse(const int* __restrict__ dst,
                                                     int* __restrict__ cnt) {
    __shared__ int h[NB1];
    int t = threadIdx.x;
    if (t < NB1) h[t] = 0;
    __syncthreads();
    int beg = blockIdx.x * 3125;  // 1024 blocks * 3125 = GE exactly
    for (int e = beg + t; e < beg + 3125; e += 256)
        atomicAdd(&h[dst[e] >> 10], 1);
    __syncthreads();
    if (t < NB1) {
        int c = h[t];
        if (c) atomicAdd(&cnt[t], c);
    }
}

__global__ void k_scan_coarse(const int* __restrict__ cnt, int* __restrict__ gcur,
                              int* __restrict__ cbase, int* __restrict__ offsets) {
    __shared__ int s[NB1];
    int t = threadIdx.x;
    if (t < NB1) s[t] = cnt[t];
    __syncthreads();
    if (t == 0) {
        int run = 0;
        for (int i = 0; i < NB1; i++) { int c = s[i]; s[i] = run; run += c; }
    }
    __syncthreads();
    if (t < NB1) { cbase[t] = s[t]; gcur[t] = s[t]; }
    if (t == 0) { cbase[NB1] = GE; offsets[GN] = GE; }
}

// block-local LDS counting sort into 98 coarse buckets, then coalesced run writes
__global__ __launch_bounds__(256) void k_bin1(const int* __restrict__ src,
                                              const int* __restrict__ dst,
                                              int* __restrict__ gcur,
                                              unsigned int* __restrict__ binned) {
    __shared__ int hist[NB1], lstart[NB1], curl[NB1], gbase[NB1];
    __shared__ unsigned int srec[B1BLK];
    __shared__ unsigned char sbuk[B1BLK];
    int t = threadIdx.x;
    if (t < NB1) hist[t] = 0;
    __syncthreads();
    int beg = blockIdx.x * B1BLK;
    unsigned int rec[20]; int bukv[20];
#pragma unroll
    for (int k = 0; k < 20; k++) {          // 256 * 20 = 5120 = B1BLK exactly
        int e = beg + t + k * 256;
        int d = dst[e];
        rec[k] = (unsigned int)src[e] | ((unsigned int)(d & 1023) << 17);
        bukv[k] = d >> 10;
        atomicAdd(&hist[bukv[k]], 1);
    }
    __syncthreads();
    if (t == 0) {
        int run = 0;
        for (int i = 0; i < NB1; i++) { lstart[i] = run; run += hist[i]; }
    }
    __syncthreads();
    if (t < NB1) {
        curl[t] = lstart[t];
        int c = hist[t];
        gbase[t] = c ? atomicAdd(&gcur[t], c) : 0;
    }
    __syncthreads();
#pragma unroll
    for (int k = 0; k < 20; k++) {
        int p = atomicAdd(&curl[bukv[k]], 1);
        srec[p] = rec[k];
        sbuk[p] = (unsigned char)bukv[k];
    }
    __syncthreads();
    // coalesced run writes: consecutive threads -> consecutive slots -> consecutive addrs
    for (int i = t; i < B1BLK; i += 256) {
        int b = sbuk[i];
        binned[gbase[b] + (i - lstart[b])] = srec[i];
    }
}

// one 1024-thread block per coarse bucket: sort to node granularity -> CSR + dinv
__global__ __launch_bounds__(1024) void k_sort2(const unsigned int* __restrict__ binned,
                                                const int* __restrict__ cbase,
                                                int* __restrict__ csr_src,
                                                int* __restrict__ offsets,
                                                float* __restrict__ dinv) {
    int b = blockIdx.x, t = threadIdx.x;
    __shared__ int hist[1024], cur[1024], wsum[16], wbase[16];
    hist[t] = 0;
    __syncthreads();
    int rbase = cbase[b], rend = cbase[b + 1];
    for (int e = rbase + t; e < rend; e += 1024)
        atomicAdd(&hist[(binned[e] >> 17) & 1023], 1);
    __syncthreads();
    int h = hist[t];
    int lane = t & 63, w = t >> 6;
    int x = h;
#pragma unroll
    for (int off = 1; off < 64; off <<= 1) {
        int y = __shfl_up(x, off);
        if (lane >= off) x += y;
    }
    if (lane == 63) wsum[w] = x;
    __syncthreads();
    if (t == 0) {
        int run = 0;
        for (int i = 0; i < 16; i++) { wbase[i] = run; run += wsum[i]; }
    }
    __syncthreads();
    int excl = wbase[w] + x - h;  // exclusive prefix within bucket
    int node = (b << 10) + t;
    if (node < GN) {
        offsets[node] = rbase + excl;
        dinv[node] = rsqrtf((float)(h + 1));  // +1 self-loop
    }
    cur[t] = excl;
    __syncthreads();
    for (int e = rbase + t; e < rend; e += 1024) {
        unsigned int v = binned[e];
        int dl = (v >> 17) & 1023;
        int p = atomicAdd(&cur[dl], 1);
        csr_src[rbase + p] = (int)(v & 0x1FFFF);
    }
}

// ---------------- GEMM: C[row] = bf16(dinv[row] * (A[row] @ W)), A fp32, C bf16 packed
__global__ __launch_bounds__(256) void k_gemm(const float* __restrict__ A,
                                              const float* __restrict__ W,
                                              const float* __restrict__ dinv,
                                              unsigned int* __restrict__ C) {
    __shared__ float Ws[64][128];
    __shared__ float As[32][68];
    int t = threadIdx.x;
    int ty = t >> 4, tx = t & 15;
    int row0 = blockIdx.x * 32;

    float4 accA[2] = {{0, 0, 0, 0}, {0, 0, 0, 0}};
    float4 accB[2] = {{0, 0, 0, 0}, {0, 0, 0, 0}};

    for (int kb = 0; kb < 128; kb += 64) {
#pragma unroll
        for (int i = 0; i < 8; i++) {
            int q = t + 256 * i;
            int kr = q >> 5;
            int c4 = (q & 31) << 2;
            *(float4*)&Ws[kr][c4] = *(const float4*)&W[(kb + kr) * 128 + c4];
        }
#pragma unroll
        for (int i = 0; i < 2; i++) {
            int q = t + 256 * i;
            int ar = q >> 4;
            int c4 = (q & 15) << 2;
            *(float4*)&As[ar][c4] = *(const float4*)&A[(size_t)(row0 + ar) * 128 + kb + c4];
        }
        __syncthreads();
#pragma unroll 8
        for (int k = 0; k < 64; k++) {
            float a0 = As[ty * 2 + 0][k];
            float a1 = As[ty * 2 + 1][k];
            float4 b0 = *(float4*)&Ws[k][tx * 4];
            float4 b1 = *(float4*)&Ws[k][64 + tx * 4];
            accA[0].x = fmaf(a0, b0.x, accA[0].x); accA[0].y = fmaf(a0, b0.y, accA[0].y);
            accA[0].z = fmaf(a0, b0.z, accA[0].z); accA[0].w = fmaf(a0, b0.w, accA[0].w);
            accB[0].x = fmaf(a0, b1.x, accB[0].x); accB[0].y = fmaf(a0, b1.y, accB[0].y);
            accB[0].z = fmaf(a0, b1.z, accB[0].z); accB[0].w = fmaf(a0, b1.w, accB[0].w);
            accA[1].x = fmaf(a1, b0.x, accA[1].x); accA[1].y = fmaf(a1, b0.y, accA[1].y);
            accA[1].z = fmaf(a1, b0.z, accA[1].z); accA[1].w = fmaf(a1, b0.w, accA[1].w);
            accB[1].x = fmaf(a1, b1.x, accB[1].x); accB[1].y = fmaf(a1, b1.y, accB[1].y);
            accB[1].z = fmaf(a1, b1.z, accB[1].z); accB[1].w = fmaf(a1, b1.w, accB[1].w);
        }
        __syncthreads();
    }
#pragma unroll
    for (int r = 0; r < 2; r++) {
        int row = row0 + ty * 2 + r;
        float dv = dinv[row];
        float4 oA = accA[r], oB = accB[r];
        uint2 pA, pB;
        pA.x = f2bf(oA.x * dv) | (f2bf(oA.y * dv) << 16);
        pA.y = f2bf(oA.z * dv) | (f2bf(oA.w * dv) << 16);
        pB.x = f2bf(oB.x * dv) | (f2bf(oB.y * dv) << 16);
        pB.y = f2bf(oB.z * dv) | (f2bf(oB.w * dv) << 16);
        *(uint2*)&C[(size_t)row * 64 + tx * 2] = pA;
        *(uint2*)&C[(size_t)row * 64 + 32 + tx * 2] = pB;
    }
}

// ------------- aggregation: out[v] = relu(dinv[v]*(sum ts[src] + ts[v]) + b)
__global__ __launch_bounds__(256) void k_aggregate(const unsigned int* __restrict__ ts,
                                                   const int* __restrict__ offsets,
                                                   const int* __restrict__ csr_src,
                                                   const float* __restrict__ dinv,
                                                   const float* __restrict__ bias,
                                                   float* __restrict__ out) {
    int node = blockIdx.x * 4 + (threadIdx.x >> 6);
    if (node >= GN) return;
    int lane = threadIdx.x & 63;
    int beg = offsets[node];
    int end = offsets[node + 1];
    float di = dinv[node];
    float ax = 0.f, ay = 0.f;
#define BFLO(u) __uint_as_float((u) << 16)
#define BFHI(u) __uint_as_float((u) & 0xffff0000u)
    int j = beg;
    for (; j + 8 <= end; j += 8) {
        int s0 = csr_src[j + 0], s1 = csr_src[j + 1], s2 = csr_src[j + 2], s3 = csr_src[j + 3];
        int s4 = csr_src[j + 4], s5 = csr_src[j + 5], s6 = csr_src[j + 6], s7 = csr_src[j + 7];
        unsigned int u0 = ts[s0 * 64 + lane], u1 = ts[s1 * 64 + lane];
        unsigned int u2 = ts[s2 * 64 + lane], u3 = ts[s3 * 64 + lane];
        unsigned int u4 = ts[s4 * 64 + lane], u5 = ts[s5 * 64 + lane];
        unsigned int u6 = ts[s6 * 64 + lane], u7 = ts[s7 * 64 + lane];
        ax += ((BFLO(u0) + BFLO(u1)) + (BFLO(u2) + BFLO(u3))) +
              ((BFLO(u4) + BFLO(u5)) + (BFLO(u6) + BFLO(u7)));
        ay += ((BFHI(u0) + BFHI(u1)) + (BFHI(u2) + BFHI(u3))) +
              ((BFHI(u4) + BFHI(u5)) + (BFHI(u6) + BFHI(u7)));
    }
    for (; j < end; j++) {
        int s = csr_src[j];
        unsigned int u = ts[s * 64 + lane];
        ax += BFLO(u); ay += BFHI(u);
    }
    unsigned int su = ts[node * 64 + lane];  // self-loop (pre-scaled by dinv[node])
    float bx = bias[lane * 2 + 0], by = bias[lane * 2 + 1];
    float ox = fmaf(di, ax + BFLO(su), bx);
    float oy = fmaf(di, ay + BFHI(su), by);
    ox = fmaxf(ox, 0.f);
    oy = fmaxf(oy, 0.f);
    float2 o = {ox, oy};
    ((float2*)out)[(size_t)node * 64 + lane] = o;
#undef BFLO
#undef BFHI
}

// ------------- mean pool per graph (batch sorted) -------------
__global__ void k_pool(const float* __restrict__ h, const int* __restrict__ batch,
                       float* __restrict__ pooled) {
    int g = blockIdx.x;
    int t = threadIdx.x;
    int f = t & 127, half = t >> 7;
    int lo = 0, hi = GN;
    while (lo < hi) { int m = (lo + hi) >> 1; if (batch[m] < g) lo = m + 1; else hi = m; }
    int start = lo;
    hi = GN;
    while (lo < hi) { int m = (lo + hi) >> 1; if (batch[m] <= g) lo = m + 1; else hi = m; }
    int end = lo;
    float a0 = 0.f, a1 = 0.f, a2 = 0.f, a3 = 0.f;
    int i = start + half;
    for (; i + 6 < end; i += 8) {
        a0 += h[(size_t)(i + 0) * 128 + f];
        a1 += h[(size_t)(i + 2) * 128 + f];
        a2 += h[(size_t)(i + 4) * 128 + f];
        a3 += h[(size_t)(i + 6) * 128 + f];
    }
    for (; i < end; i += 2) a0 += h[(size_t)i * 128 + f];
    float s = (a0 + a1) + (a2 + a3);
    __shared__ float red[256];
    red[t] = s;
    __syncthreads();
    if (t < 128) {
        float tot = red[t] + red[t + 128];
        pooled[g * 128 + f] = tot / fmaxf((float)(end - start), 1.0f);
    }
}

// ------------- value head -------------
__global__ void k_value(const float* __restrict__ pooled, const float* __restrict__ Wv,
                        const float* __restrict__ bv, float* __restrict__ out) {
    int g = threadIdx.x;
    const float4* p4 = (const float4*)(pooled + g * 128);
    const float4* w4 = (const float4*)Wv;
    float s = 0.f;
#pragma unroll 8
    for (int i = 0; i < 32; i++) {
        float4 a = p4[i], b = w4[i];
        s += a.x * b.x + a.y * b.y + a.z * b.z + a.w * b.w;
    }
    out[g] = tanhf(s + bv[0]);
}

// ------------- policy head -------------
__global__ __launch_bounds__(256) void k_policy(const float* __restrict__ pooled,
                                                const float* __restrict__ Wp,
                                                const float* __restrict__ bp,
                                                float* __restrict__ out) {
    int g = blockIdx.x;
    int t = threadIdx.x;
    __shared__ float pr[128];
    __shared__ float red[256];
    if (t < 128) pr[t] = pooled[g * 128 + t];
    __syncthreads();
    float acc0 = bp[t + 0], acc1 = bp[t + 256], acc2 = bp[t + 512], acc3 = bp[t + 768];
    for (int k = 0; k < 128; k++) {
        float pv = pr[k];
        const float* wr = Wp + (size_t)k * 1024;
        acc0 = fmaf(pv, wr[t + 0],   acc0);
        acc1 = fmaf(pv, wr[t + 256], acc1);
        acc2 = fmaf(pv, wr[t + 512], acc2);
        acc3 = fmaf(pv, wr[t + 768], acc3);
    }
    float m = fmaxf(fmaxf(acc0, acc1), fmaxf(acc2, acc3));
    red[t] = m;
    __syncthreads();
    for (int off = 128; off > 0; off >>= 1) {
        if (t < off) red[t] = fmaxf(red[t], red[t + off]);
        __syncthreads();
    }
    float mx = red[0];
    __syncthreads();
    float e0 = __expf(acc0 - mx), e1 = __expf(acc1 - mx);
    float e2 = __expf(acc2 - mx), e3 = __expf(acc3 - mx);
    red[t] = (e0 + e1) + (e2 + e3);
    __syncthreads();
    for (int off = 128; off > 0; off >>= 1) {
        if (t < off) red[t] += red[t + off];
        __syncthreads();
    }
    float inv = 1.0f / red[0];
    out[(size_t)g * 1024 + t + 0]   = e0 * inv;
    out[(size_t)g * 1024 + t + 256] = e1 * inv;
    out[(size_t)g * 1024 + t + 512] = e2 * inv;
    out[(size_t)g * 1024 + t + 768] = e3 * inv;
}

extern "C" void kernel_launch(void* const* d_in, const int* in_sizes, int n_in,
                              void* d_out, int out_size, void* d_ws, size_t ws_size,
                              hipStream_t stream) {
    const float* x    = (const float*)d_in[0];
    const int*   ei   = (const int*)d_in[1];
    const int*   srcA = ei;        // edge_index[0]
    const int*   dstA = ei + GE;   // edge_index[1]
    const int*   batch = (const int*)d_in[2];
    const float* W1 = (const float*)d_in[3];
    const float* b1 = (const float*)d_in[4];
    const float* W2 = (const float*)d_in[5];
    const float* b2 = (const float*)d_in[6];
    const float* Wv = (const float*)d_in[7];
    const float* bv = (const float*)d_in[8];
    const float* Wp = (const float*)d_in[9];
    const float* bp = (const float*)d_in[10];
    float* out = (float*)d_out;

    char* ws = (char*)d_ws;
    float* bufH = (float*)ws;        ws += (size_t)GN * 128 * 4;       // 51.2 MB fp32 h
    unsigned int* ts_bf = (unsigned int*)ws; ws += (size_t)GN * 64 * 4; // 25.6 MB bf16 ts
    float* pooled = (float*)ws;      ws += (size_t)GB * 128 * 4;
    float* dinv = (float*)ws;        ws += (size_t)100352 * 4;
    int*   csr_src = (int*)ws;       ws += (size_t)GE * 4;             // 12.8 MB
    int*   offsets = (int*)ws;       ws += (size_t)100352 * 4;
    int*   coarse_cnt = (int*)ws;    ws += 128 * 4;
    int*   gcur = (int*)ws;          ws += 128 * 4;
    int*   cbase = (int*)ws;         ws += 128 * 4;
    unsigned int* binned = ts_bf;    // alias: consumed by k_sort2 before gemm1 writes ts

    // --- CSR build ---
    hipMemsetAsync(coarse_cnt, 0, NB1 * 4, stream);
    k_hist_coarse<<<1024, 256, 0, stream>>>(dstA, coarse_cnt);
    k_scan_coarse<<<1, 128, 0, stream>>>(coarse_cnt, gcur, cbase, offsets);
    k_bin1<<<NBIN1, 256, 0, stream>>>(srcA, dstA, gcur, binned);
    k_sort2<<<NB1, 1024, 0, stream>>>(binned, cbase, csr_src, offsets, dinv);

    // --- layer 1: ts = bf16(dinv .* (x @ W1)); h1 = relu(dinv*(gather + self) + b1) ---
    k_gemm<<<GN / 32, 256, 0, stream>>>(x, W1, dinv, ts_bf);
    k_aggregate<<<GN / 4, 256, 0, stream>>>(ts_bf, offsets, csr_src, dinv, b1, bufH);

    // --- layer 2 ---
    k_gemm<<<GN / 32, 256, 0, stream>>>(bufH, W2, dinv, ts_bf);
    k_aggregate<<<GN / 4, 256, 0, stream>>>(ts_bf, offsets, csr_src, dinv, b2, bufH);

    // --- pool + heads ---
    k_pool<<<GB, 256, 0, stream>>>(bufH, batch, pooled);
    k_value<<<1, 256, 0, stream>>>(pooled, Wv, bv, out);
    k_policy<<<GB, 256, 0, stream>>>(pooled, Wp, bp, out + GB);
}

// Round 7
// 468.035 us; speedup vs baseline: 2.1511x; 1.0529x over previous
//
#include <hip/hip_runtime.h>
#include <hip/hip_bf16.h>

#define GN 100000   // nodes
#define GE 3200000  // edges
#define GH 128      // feature/hidden width
#define GA 1024     // actions
#define GB 256      // graphs

#define NBUK 391    // buckets of 256 nodes (ceil(GN/256))
#define B1BLK 5120  // edges per k_bin1 block
#define NBIN1 625   // k_bin1 blocks: 625 * 5120 = GE exactly

// round-to-nearest-even fp32 -> bf16 (as ushort)
__device__ __forceinline__ unsigned int f2bf(float f) {
    unsigned int u = __float_as_uint(f);
    return (u + 0x7fffu + ((u >> 16) & 1u)) >> 16;
}
__device__ __forceinline__ float bflo(unsigned int u) { return __uint_as_float(u << 16); }
__device__ __forceinline__ float bfhi(unsigned int u) { return __uint_as_float(u & 0xffff0000u); }

// ---------------- CSR build: coarse bin (LDS-staged coalesced) + in-bucket sort ----

__global__ __launch_bounds__(256) void k_hist_coarse(const int* __restrict__ dst,
                                                     int* __restrict__ cnt) {
    __shared__ int h[NBUK];
    int t = threadIdx.x;
    for (int i = t; i < NBUK; i += 256) h[i] = 0;
    __syncthreads();
    int beg = blockIdx.x * 3125;  // 1024 blocks * 3125 = GE exactly
    for (int e = beg + t; e < beg + 3125; e += 256)
        atomicAdd(&h[dst[e] >> 8], 1);
    __syncthreads();
    for (int i = t; i < NBUK; i += 256) {
        int c = h[i];
        if (c) atomicAdd(&cnt[i], c);
    }
}

// parallel exclusive scan of 391 counts (padded to 512), 2 elements/thread
__global__ __launch_bounds__(256) void k_scan_coarse(const int* __restrict__ cnt,
                                                     int* __restrict__ gcur,
                                                     int* __restrict__ cbase,
                                                     int* __restrict__ offsets) {
    __shared__ int wsc[4];
    int t = threadIdx.x;
    int i0 = 2 * t, i1 = 2 * t + 1;
    int v0 = (i0 < NBUK) ? cnt[i0] : 0;
    int v1 = (i1 < NBUK) ? cnt[i1] : 0;
    int s = v0 + v1;
    int lane = t & 63, w = t >> 6;
    int x = s;
#pragma unroll
    for (int off = 1; off < 64; off <<= 1) {
        int y = __shfl_up(x, off);
        if (lane >= off) x += y;
    }
    if (lane == 63) wsc[w] = x;
    __syncthreads();
    int wo = 0;
#pragma unroll
    for (int i = 0; i < 4; i++)
        if (i < w) wo += wsc[i];
    int excl = wo + x - s;
    if (i0 < NBUK) { cbase[i0] = excl; gcur[i0] = excl; }
    if (i1 < NBUK) { cbase[i1] = excl + v0; gcur[i1] = excl + v0; }
    if (t == 0) { cbase[NBUK] = GE; offsets[GN] = GE; }
}

// block-local LDS counting sort into 391 buckets, then coalesced run writes
__global__ __launch_bounds__(256) void k_bin1(const int* __restrict__ src,
                                              const int* __restrict__ dst,
                                              int* __restrict__ gcur,
                                              unsigned int* __restrict__ binned) {
    __shared__ int hist[512], lstart[512];
    __shared__ int curl[NBUK], gbase[NBUK];
    __shared__ unsigned int srec[B1BLK];
    __shared__ unsigned short sbuk[B1BLK];
    __shared__ int wsc[4];
    int t = threadIdx.x;
    hist[t] = 0; hist[t + 256] = 0;
    __syncthreads();
    int beg = blockIdx.x * B1BLK;
    unsigned int rec[20]; int bukv[20];
#pragma unroll
    for (int k = 0; k < 20; k++) {          // 256 * 20 = 5120 = B1BLK exactly
        int e = beg + t + k * 256;
        int d = dst[e];
        rec[k] = (unsigned int)src[e] | ((unsigned int)(d & 255) << 17);
        bukv[k] = d >> 8;
        atomicAdd(&hist[bukv[k]], 1);
    }
    __syncthreads();
    // parallel scan of 512 bucket counts, 2/thread
    int v0 = hist[2 * t], v1 = hist[2 * t + 1];
    int s = v0 + v1;
    int lane = t & 63, w = t >> 6;
    int x = s;
#pragma unroll
    for (int off = 1; off < 64; off <<= 1) {
        int y = __shfl_up(x, off);
        if (lane >= off) x += y;
    }
    if (lane == 63) wsc[w] = x;
    __syncthreads();
    int wo = 0;
#pragma unroll
    for (int i = 0; i < 4; i++)
        if (i < w) wo += wsc[i];
    int excl = wo + x - s;
    lstart[2 * t] = excl;
    lstart[2 * t + 1] = excl + v0;
    __syncthreads();
    for (int i = t; i < NBUK; i += 256) {
        curl[i] = lstart[i];
        int c = hist[i];
        gbase[i] = c ? atomicAdd(&gcur[i], c) : 0;
    }
    __syncthreads();
#pragma unroll
    for (int k = 0; k < 20; k++) {
        int p = atomicAdd(&curl[bukv[k]], 1);
        srec[p] = rec[k];
        sbuk[p] = (unsigned short)bukv[k];
    }
    __syncthreads();
    // coalesced run writes: consecutive threads -> consecutive slots -> consecutive addrs
    for (int i = t; i < B1BLK; i += 256) {
        int b = sbuk[i];
        binned[gbase[b] + (i - lstart[b])] = srec[i];
    }
}

// one 256-thread block per bucket: sort to node granularity -> CSR + dinv
__global__ __launch_bounds__(256) void k_sort2(const unsigned int* __restrict__ binned,
                                               const int* __restrict__ cbase,
                                               int* __restrict__ csr_src,
                                               int* __restrict__ offsets,
                                               float* __restrict__ dinv) {
    int b = blockIdx.x, t = threadIdx.x;
    __shared__ int hist[256], cur[256], wsum[4];
    hist[t] = 0;
    __syncthreads();
    int rbase = cbase[b], rend = cbase[b + 1];
    for (int e = rbase + t; e < rend; e += 256)
        atomicAdd(&hist[(binned[e] >> 17) & 255], 1);
    __syncthreads();
    int h = hist[t];
    int lane = t & 63, w = t >> 6;
    int x = h;
#pragma unroll
    for (int off = 1; off < 64; off <<= 1) {
        int y = __shfl_up(x, off);
        if (lane >= off) x += y;
    }
    if (lane == 63) wsum[w] = x;
    __syncthreads();
    int wo = 0;
#pragma unroll
    for (int i = 0; i < 4; i++)
        if (i < w) wo += wsum[i];
    int excl = wo + x - h;  // exclusive prefix within bucket
    int node = (b << 8) + t;
    if (node < GN) {
        offsets[node] = rbase + excl;
        dinv[node] = rsqrtf((float)(h + 1));  // +1 self-loop
    }
    cur[t] = excl;
    __syncthreads();
    for (int e = rbase + t; e < rend; e += 256) {
        unsigned int v = binned[e];
        int dl = (v >> 17) & 255;
        int p = atomicAdd(&cur[dl], 1);
        csr_src[rbase + p] = (int)(v & 0x1FFFF);
    }
}

// ---------------- GEMM (fp32 A): C[row] = bf16(dinv[row] * (A[row] @ W))
__global__ __launch_bounds__(256) void k_gemm_f32(const float* __restrict__ A,
                                                  const float* __restrict__ W,
                                                  const float* __restrict__ dinv,
                                                  unsigned int* __restrict__ C) {
    __shared__ float Ws[64][128];
    __shared__ float As[32][68];
    int t = threadIdx.x;
    int ty = t >> 4, tx = t & 15;
    int row0 = blockIdx.x * 32;

    float4 accA[2] = {{0, 0, 0, 0}, {0, 0, 0, 0}};
    float4 accB[2] = {{0, 0, 0, 0}, {0, 0, 0, 0}};

    for (int kb = 0; kb < 128; kb += 64) {
#pragma unroll
        for (int i = 0; i < 8; i++) {
            int q = t + 256 * i;
            int kr = q >> 5;
            int c4 = (q & 31) << 2;
            *(float4*)&Ws[kr][c4] = *(const float4*)&W[(kb + kr) * 128 + c4];
        }
#pragma unroll
        for (int i = 0; i < 2; i++) {
            int q = t + 256 * i;
            int ar = q >> 4;
            int c4 = (q & 15) << 2;
            *(float4*)&As[ar][c4] = *(const float4*)&A[(size_t)(row0 + ar) * 128 + kb + c4];
        }
        __syncthreads();
#pragma unroll 8
        for (int k = 0; k < 64; k++) {
            float a0 = As[ty * 2 + 0][k];
            float a1 = As[ty * 2 + 1][k];
            float4 b0 = *(float4*)&Ws[k][tx * 4];
            float4 b1 = *(float4*)&Ws[k][64 + tx * 4];
            accA[0].x = fmaf(a0, b0.x, accA[0].x); accA[0].y = fmaf(a0, b0.y, accA[0].y);
            accA[0].z = fmaf(a0, b0.z, accA[0].z); accA[0].w = fmaf(a0, b0.w, accA[0].w);
            accB[0].x = fmaf(a0, b1.x, accB[0].x); accB[0].y = fmaf(a0, b1.y, accB[0].y);
            accB[0].z = fmaf(a0, b1.z, accB[0].z); accB[0].w = fmaf(a0, b1.w, accB[0].w);
            accA[1].x = fmaf(a1, b0.x, accA[1].x); accA[1].y = fmaf(a1, b0.y, accA[1].y);
            accA[1].z = fmaf(a1, b0.z, accA[1].z); accA[1].w = fmaf(a1, b0.w, accA[1].w);
            accB[1].x = fmaf(a1, b1.x, accB[1].x); accB[1].y = fmaf(a1, b1.y, accB[1].y);
            accB[1].z = fmaf(a1, b1.z, accB[1].z); accB[1].w = fmaf(a1, b1.w, accB[1].w);
        }
        __syncthreads();
    }
#pragma unroll
    for (int r = 0; r < 2; r++) {
        int row = row0 + ty * 2 + r;
        float dv = dinv[row];
        float4 oA = accA[r], oB = accB[r];
        uint2 pA, pB;
        pA.x = f2bf(oA.x * dv) | (f2bf(oA.y * dv) << 16);
        pA.y = f2bf(oA.z * dv) | (f2bf(oA.w * dv) << 16);
        pB.x = f2bf(oB.x * dv) | (f2bf(oB.y * dv) << 16);
        pB.y = f2bf(oB.z * dv) | (f2bf(oB.w * dv) << 16);
        *(uint2*)&C[(size_t)row * 64 + tx * 2] = pA;
        *(uint2*)&C[(size_t)row * 64 + 32 + tx * 2] = pB;
    }
}

// ---------------- GEMM (bf16 A): same, A rows are 64 packed uints
__global__ __launch_bounds__(256) void k_gemm_bf16(const unsigned int* __restrict__ A,
                                                   const float* __restrict__ W,
                                                   const float* __restrict__ dinv,
                                                   unsigned int* __restrict__ C) {
    __shared__ float Ws[64][128];
    __shared__ float As[32][68];
    int t = threadIdx.x;
    int ty = t >> 4, tx = t & 15;
    int row0 = blockIdx.x * 32;

    float4 accA[2] = {{0, 0, 0, 0}, {0, 0, 0, 0}};
    float4 accB[2] = {{0, 0, 0, 0}, {0, 0, 0, 0}};

    for (int kb = 0; kb < 128; kb += 64) {
#pragma unroll
        for (int i = 0; i < 8; i++) {
            int q = t + 256 * i;
            int kr = q >> 5;
            int c4 = (q & 31) << 2;
            *(float4*)&Ws[kr][c4] = *(const float4*)&W[(kb + kr) * 128 + c4];
        }
        {
            int ar = t >> 3;
            int cu = (t & 7) * 4;  // uint col within k-block (32 uints = 64 cols)
            uint4 av = *(const uint4*)&A[(size_t)(row0 + ar) * 64 + (kb >> 1) + cu];
            unsigned int uu[4] = {av.x, av.y, av.z, av.w};
#pragma unroll
            for (int i = 0; i < 4; i++) {
                As[ar][(cu + i) * 2 + 0] = bflo(uu[i]);
                As[ar][(cu + i) * 2 + 1] = bfhi(uu[i]);
            }
        }
        __syncthreads();
#pragma unroll 8
        for (int k = 0; k < 64; k++) {
            float a0 = As[ty * 2 + 0][k];
            float a1 = As[ty * 2 + 1][k];
            float4 b0 = *(float4*)&Ws[k][tx * 4];
            float4 b1 = *(float4*)&Ws[k][64 + tx * 4];
            accA[0].x = fmaf(a0, b0.x, accA[0].x); accA[0].y = fmaf(a0, b0.y, accA[0].y);
            accA[0].z = fmaf(a0, b0.z, accA[0].z); accA[0].w = fmaf(a0, b0.w, accA[0].w);
            accB[0].x = fmaf(a0, b1.x, accB[0].x); accB[0].y = fmaf(a0, b1.y, accB[0].y);
            accB[0].z = fmaf(a0, b1.z, accB[0].z); accB[0].w = fmaf(a0, b1.w, accB[0].w);
            accA[1].x = fmaf(a1, b0.x, accA[1].x); accA[1].y = fmaf(a1, b0.y, accA[1].y);
            accA[1].z = fmaf(a1, b0.z, accA[1].z); accA[1].w = fmaf(a1, b0.w, accA[1].w);
            accB[1].x = fmaf(a1, b1.x, accB[1].x); accB[1].y = fmaf(a1, b1.y, accB[1].y);
            accB[1].z = fmaf(a1, b1.z, accB[1].z); accB[1].w = fmaf(a1, b1.w, accB[1].w);
        }
        __syncthreads();
    }
#pragma unroll
    for (int r = 0; r < 2; r++) {
        int row = row0 + ty * 2 + r;
        float dv = dinv[row];
        float4 oA = accA[r], oB = accB[r];
        uint2 pA, pB;
        pA.x = f2bf(oA.x * dv) | (f2bf(oA.y * dv) << 16);
        pA.y = f2bf(oA.z * dv) | (f2bf(oA.w * dv) << 16);
        pB.x = f2bf(oB.x * dv) | (f2bf(oB.y * dv) << 16);
        pB.y = f2bf(oB.z * dv) | (f2bf(oB.w * dv) << 16);
        *(uint2*)&C[(size_t)row * 64 + tx * 2] = pA;
        *(uint2*)&C[(size_t)row * 64 + 32 + tx * 2] = pB;
    }
}

// ------------- aggregation: h[v] = relu(dinv[v]*(sum ts[src] + ts[v]) + b), bf16 out
__global__ __launch_bounds__(256) void k_aggregate(const unsigned int* __restrict__ ts,
                                                   const int* __restrict__ offsets,
                                                   const int* __restrict__ csr_src,
                                                   const float* __restrict__ dinv,
                                                   const float* __restrict__ bias,
                                                   unsigned int* __restrict__ out) {
    int node = blockIdx.x * 4 + (threadIdx.x >> 6);
    if (node >= GN) return;
    int lane = threadIdx.x & 63;
    int beg = offsets[node];
    int end = offsets[node + 1];
    float di = dinv[node];
    float ax = 0.f, ay = 0.f;
    for (int base = beg; base < end; base += 64) {
        int n = end - base; if (n > 64) n = 64;
        int myidx = (lane < n) ? csr_src[base + lane] : 0;  // coalesced index load
        int k = 0;
        for (; k + 16 <= n; k += 16) {
            unsigned int u[16];
#pragma unroll
            for (int q = 0; q < 16; q++) {
                int s = __shfl(myidx, k + q);
                u[q] = ts[s * 64 + lane];
            }
#pragma unroll
            for (int q = 0; q < 16; q++) { ax += bflo(u[q]); ay += bfhi(u[q]); }
        }
        for (; k + 4 <= n; k += 4) {
            unsigned int u[4];
#pragma unroll
            for (int q = 0; q < 4; q++) {
                int s = __shfl(myidx, k + q);
                u[q] = ts[s * 64 + lane];
            }
#pragma unroll
            for (int q = 0; q < 4; q++) { ax += bflo(u[q]); ay += bfhi(u[q]); }
        }
        for (; k < n; k++) {
            int s = __shfl(myidx, k);
            unsigned int u = ts[s * 64 + lane];
            ax += bflo(u); ay += bfhi(u);
        }
    }
    unsigned int su = ts[(size_t)node * 64 + lane];  // self-loop (pre-scaled)
    float bx = bias[lane * 2 + 0], by = bias[lane * 2 + 1];
    float ox = fmaxf(fmaf(di, ax + bflo(su), bx), 0.f);
    float oy = fmaxf(fmaf(di, ay + bfhi(su), by), 0.f);
    out[(size_t)node * 64 + lane] = f2bf(ox) | (f2bf(oy) << 16);
}

// ------------- mean pool per graph (batch sorted), bf16 h input -------------
__global__ __launch_bounds__(256) void k_pool(const unsigned int* __restrict__ h,
                                              const int* __restrict__ batch,
                                              float* __restrict__ pooled) {
    int g = blockIdx.x;
    int t = threadIdx.x;
    int f = t & 63, part = t >> 6;  // f: uint col, part: 4-way row split
    int lo = 0, hi = GN;
    while (lo < hi) { int m = (lo + hi) >> 1; if (batch[m] < g) lo = m + 1; else hi = m; }
    int start = lo;
    hi = GN;
    while (lo < hi) { int m = (lo + hi) >> 1; if (batch[m] <= g) lo = m + 1; else hi = m; }
    int end = lo;
    float ax = 0.f, ay = 0.f;
    for (int i = start + part; i < end; i += 4) {
        unsigned int u = h[(size_t)i * 64 + f];
        ax += bflo(u); ay += bfhi(u);
    }
    __shared__ float redx[256], redy[256];
    redx[t] = ax; redy[t] = ay;
    __syncthreads();
    if (part == 0) {
        float sx = redx[f] + redx[f + 64] + redx[f + 128] + redx[f + 192];
        float sy = redy[f] + redy[f + 64] + redy[f + 128] + redy[f + 192];
        float inv = 1.0f / fmaxf((float)(end - start), 1.0f);
        pooled[g * 128 + 2 * f + 0] = sx * inv;
        pooled[g * 128 + 2 * f + 1] = sy * inv;
    }
}

// ------------- value head -------------
__global__ void k_value(const float* __restrict__ pooled, const float* __restrict__ Wv,
                        const float* __restrict__ bv, float* __restrict__ out) {
    int g = threadIdx.x;
    const float4* p4 = (const float4*)(pooled + g * 128);
    const float4* w4 = (const float4*)Wv;
    float s = 0.f;
#pragma unroll 8
    for (int i = 0; i < 32; i++) {
        float4 a = p4[i], b = w4[i];
        s += a.x * b.x + a.y * b.y + a.z * b.z + a.w * b.w;
    }
    out[g] = tanhf(s + bv[0]);
}

// ------------- policy head -------------
__global__ __launch_bounds__(256) void k_policy(const float* __restrict__ pooled,
                                                const float* __restrict__ Wp,
                                                const float* __restrict__ bp,
                                                float* __restrict__ out) {
    int g = blockIdx.x;
    int t = threadIdx.x;
    __shared__ float pr[128];
    __shared__ float red[256];
    if (t < 128) pr[t] = pooled[g * 128 + t];
    __syncthreads();
    float acc0 = bp[t + 0], acc1 = bp[t + 256], acc2 = bp[t + 512], acc3 = bp[t + 768];
    for (int k = 0; k < 128; k++) {
        float pv = pr[k];
        const float* wr = Wp + (size_t)k * 1024;
        acc0 = fmaf(pv, wr[t + 0],   acc0);
        acc1 = fmaf(pv, wr[t + 256], acc1);
        acc2 = fmaf(pv, wr[t + 512], acc2);
        acc3 = fmaf(pv, wr[t + 768], acc3);
    }
    float m = fmaxf(fmaxf(acc0, acc1), fmaxf(acc2, acc3));
    red[t] = m;
    __syncthreads();
    for (int off = 128; off > 0; off >>= 1) {
        if (t < off) red[t] = fmaxf(red[t], red[t + off]);
        __syncthreads();
    }
    float mx = red[0];
    __syncthreads();
    float e0 = __expf(acc0 - mx), e1 = __expf(acc1 - mx);
    float e2 = __expf(acc2 - mx), e3 = __expf(acc3 - mx);
    red[t] = (e0 + e1) + (e2 + e3);
    __syncthreads();
    for (int off = 128; off > 0; off >>= 1) {
        if (t < off) red[t] += red[t + off];
        __syncthreads();
    }
    float inv = 1.0f / red[0];
    out[(size_t)g * 1024 + t + 0]   = e0 * inv;
    out[(size_t)g * 1024 + t + 256] = e1 * inv;
    out[(size_t)g * 1024 + t + 512] = e2 * inv;
    out[(size_t)g * 1024 + t + 768] = e3 * inv;
}

extern "C" void kernel_launch(void* const* d_in, const int* in_sizes, int n_in,
                              void* d_out, int out_size, void* d_ws, size_t ws_size,
                              hipStream_t stream) {
    const float* x    = (const float*)d_in[0];
    const int*   ei   = (const int*)d_in[1];
    const int*   srcA = ei;        // edge_index[0]
    const int*   dstA = ei + GE;   // edge_index[1]
    const int*   batch = (const int*)d_in[2];
    const float* W1 = (const float*)d_in[3];
    const float* b1 = (const float*)d_in[4];
    const float* W2 = (const float*)d_in[5];
    const float* b2 = (const float*)d_in[6];
    const float* Wv = (const float*)d_in[7];
    const float* bv = (const float*)d_in[8];
    const float* Wp = (const float*)d_in[9];
    const float* bp = (const float*)d_in[10];
    float* out = (float*)d_out;

    char* ws = (char*)d_ws;
    unsigned int* bufH = (unsigned int*)ws;  ws += (size_t)GN * 64 * 4;  // 25.6 MB bf16 h
    unsigned int* ts_bf = (unsigned int*)ws; ws += (size_t)GN * 64 * 4;  // 25.6 MB bf16 ts
    float* pooled = (float*)ws;      ws += (size_t)GB * 128 * 4;
    float* dinv = (float*)ws;        ws += (size_t)100352 * 4;
    int*   csr_src = (int*)ws;       ws += (size_t)GE * 4;               // 12.8 MB
    int*   offsets = (int*)ws;       ws += (size_t)100352 * 4;
    int*   coarse_cnt = (int*)ws;    ws += 512 * 4;
    int*   gcur = (int*)ws;          ws += 512 * 4;
    int*   cbase = (int*)ws;         ws += 512 * 4;
    unsigned int* binned = ts_bf;    // alias: consumed by k_sort2 before gemm1 writes ts

    // --- CSR build ---
    hipMemsetAsync(coarse_cnt, 0, NBUK * 4, stream);
    k_hist_coarse<<<1024, 256, 0, stream>>>(dstA, coarse_cnt);
    k_scan_coarse<<<1, 256, 0, stream>>>(coarse_cnt, gcur, cbase, offsets);
    k_bin1<<<NBIN1, 256, 0, stream>>>(srcA, dstA, gcur, binned);
    k_sort2<<<NBUK, 256, 0, stream>>>(binned, cbase, csr_src, offsets, dinv);

    // --- layer 1: ts = bf16(dinv .* (x @ W1)); h1 = relu(dinv*(gather + self) + b1) ---
    k_gemm_f32<<<GN / 32, 256, 0, stream>>>(x, W1, dinv, ts_bf);
    k_aggregate<<<GN / 4, 256, 0, stream>>>(ts_bf, offsets, csr_src, dinv, b1, bufH);

    // --- layer 2 ---
    k_gemm_bf16<<<GN / 32, 256, 0, stream>>>(bufH, W2, dinv, ts_bf);
    k_aggregate<<<GN / 4, 256, 0, stream>>>(ts_bf, offsets, csr_src, dinv, b2, bufH);

    // --- pool + heads ---
    k_pool<<<GB, 256, 0, stream>>>(bufH, batch, pooled);
    k_value<<<1, 256, 0, stream>>>(pooled, Wv, bv, out);
    k_policy<<<GB, 256, 0, stream>>>(pooled, Wp, bp, out + GB);
}